// Round 7
// baseline (146.601 us; speedup 1.0000x reference)
//
#include <hip/hip_runtime.h>

// LPC synthesis (AR(15), frame-hopped coefs) + de-emphasis IIR.
//
// R13: CROSS-TILE SOFTWARE PIPELINE (convoy breaker). R12 measured ~41 us
// with VALU-busy ~12 us and memory ~15.5 us: the whole grid is resident
// and every block runs fetch -> compute -> store in lockstep, so HBM and
// VALU phases never overlap (VALUBusy ~30%, hbm avg ~2.3 TB/s). Fix:
// each block processes kNT=2 consecutive half-frame tiles with
// double-buffered LDS; the global loads for tile t+1 are issued BEFORE
// the compute of tile t (register prefetch, ~2700 cyc of compute covers
// ~900 cyc HBM latency), and the stores of tile t drain under the
// compute of tile t+1. Steady state: fetch(t+1) || compute(t) ||
// store-drain(t-1) per block, at 6 blocks/CU.
//
// Numerics identical to R12 (absmax 0.015625 = fp16-z ulp floor):
//  - one lane per 40-sample half-frame; AR warm-up 48 samples (rho^48);
//  - de-emph z computed per half-frame locally, init patched via 9-term
//    Neumann over neighbor zends (r = 0.97^40, residual ~4e-4);
//  - fp16 excit staging + in-place fp16 z writeback; coalesced store
//    phase (R8 proved scattered 16B/lane stores write-amplify 2.6x);
//  - taps from global, negation folded into fmaf (VOP3 -src, free);
//  - pre-signal inputs masked to zero -> first frames exact.
// R3 lesson: no runtime-indexed per-lane arrays (ring x[16] + tap regs
// are all compile-time indexed; tile rotation is explicit reg copies).

namespace {
constexpr int kFS = 80;         // frame shift
constexpr int kHS = 40;         // samples per half-frame
constexpr int kF = 3000;        // frames per batch
constexpr int kH = 2 * kF;      // 6000 half-frames per batch
constexpr int kL = kFS * kF;    // 240000
constexpr int kOrder = 16;
constexpr int kB = 64;
constexpr float kEmph = 0.97f;
constexpr int kThreads = 128;   // 2 waves/block
constexpr int kJunk = 9;        // 9-term correction needs 9 lead lanes
constexpr int kEmitH = kThreads - kJunk;        // 119 half-frames/tile
constexpr int kSEH = 44;        // LDS halves per slot (88 B, 8B-aligned)
constexpr int kNT = 2;          // tiles per block (pipeline depth)
constexpr int kTiles = (kH + kEmitH - 1) / kEmitH;  // 51
constexpr int kCols = (kTiles + kNT - 1) / kNT;     // 26
constexpr float kLg97 = -4.3943347e-2f;  // log2(0.97)
// powers of r = 0.97^40
constexpr float kR1 = 0.2957118f;
constexpr float kR2 = 0.08744547f;
constexpr float kR3 = 0.02585867f;
constexpr float kR4 = 0.00764671f;
constexpr float kR5 = 0.00226126f;
constexpr float kR6 = 6.6867e-4f;
constexpr float kR7 = 1.9773e-4f;
constexpr float kR8 = 5.8472e-5f;

typedef float vfloat4 __attribute__((ext_vector_type(4)));
typedef _Float16 half4v __attribute__((ext_vector_type(4)));
}  // namespace

__global__ __launch_bounds__(kThreads, 3) void lpc_synth_kernel(
    const float* __restrict__ excit, const float* __restrict__ coef,
    float* __restrict__ out) {
  __shared__ _Float16 s_e[2][kThreads * kSEH];  // 2 x 11264 B
  __shared__ float s_zend[kThreads];            // per-lane zh
  __shared__ float s_zp[kThreads];              // per-output Zp

  const int tid = threadIdx.x;
  const int b = blockIdx.y;
  const int tile0 = blockIdx.x * kNT;

  const float* __restrict__ ebase = excit + (size_t)b * kL;
  const float* __restrict__ cbase = coef + (size_t)b * kF * kOrder;

  vfloat4 ex[10];           // prefetched excit for the tile about to stage
  vfloat4 tpc[4], tcc[4];   // taps (prev/cur frame) for current tile
  vfloat4 tpn[4], tcn[4];   // taps for next tile (prefetch)
  int htc, htn;

  // Issue all global loads for one tile: excit (10 x dwordx4 -> ex) and
  // both tap sets. Phantom tiles (ht >= kH) clamp to valid addresses.
#define LOAD_TILE(TI, TPD, TCD, HTD)                                       \
  {                                                                        \
    const int ht_ = (TI)*kEmitH + tid - kJunk;                             \
    (HTD) = ht_;                                                           \
    const int hc_ = min(max(ht_, 0), kH - 1);                              \
    const int hw_ = min(max(ht_ - 2, 0), kH - 1);                          \
    const vfloat4* __restrict__ ep_ =                                      \
        (const vfloat4*)(ebase + (size_t)hc_ * kHS);                       \
    const vfloat4* __restrict__ pp_ =                                      \
        (const vfloat4*)(cbase + (size_t)(hw_ >> 1) * kOrder);             \
    const vfloat4* __restrict__ cc_ =                                      \
        (const vfloat4*)(cbase + (size_t)(hc_ >> 1) * kOrder);             \
    _Pragma("unroll") for (int j = 0; j < 10; ++j) ex[j] = ep_[j];         \
    _Pragma("unroll") for (int j = 0; j < 4; ++j) {                        \
      (TPD)[j] = pp_[j];                                                   \
      (TCD)[j] = cc_[j];                                                   \
    }                                                                      \
  }

  // One AR sample; 3 partial accumulators keep the cross-sample critical
  // path at 1 fma + 1 add (8 cyc). Taps consumed as -A[k] via the fmaf
  // neg source modifier (zero cost).
#define AR_SAMPLE(A, s, e_in, ACC)                                         \
  float ACC;                                                               \
  {                                                                        \
    float t0 = (e_in);                                                     \
    t0 = fmaf(-A[14], x[((s)-15) & 15], t0);                               \
    t0 = fmaf(-A[13], x[((s)-14) & 15], t0);                               \
    t0 = fmaf(-A[12], x[((s)-13) & 15], t0);                               \
    t0 = fmaf(-A[11], x[((s)-12) & 15], t0);                               \
    t0 = fmaf(-A[10], x[((s)-11) & 15], t0);                               \
    float t1 = -A[9] * x[((s)-10) & 15];                                   \
    t1 = fmaf(-A[8], x[((s)-9) & 15], t1);                                 \
    t1 = fmaf(-A[7], x[((s)-8) & 15], t1);                                 \
    t1 = fmaf(-A[6], x[((s)-7) & 15], t1);                                 \
    t1 = fmaf(-A[5], x[((s)-6) & 15], t1);                                 \
    float t2 = -A[4] * x[((s)-5) & 15];                                    \
    t2 = fmaf(-A[3], x[((s)-4) & 15], t2);                                 \
    t2 = fmaf(-A[2], x[((s)-3) & 15], t2);                                 \
    t2 = fmaf(-A[1], x[((s)-2) & 15], t2);                                 \
    const float t01 = t0 + t1;               /* off critical path */       \
    t2 = fmaf(-A[0], x[((s)-1) & 15], t2);   /* critical: 1 fma */         \
    ACC = t01 + t2;                          /* + 1 add */                 \
    x[(s)&15] = ACC;                                                       \
  }

  // ---- Prologue: fetch tile0 (ramp; not overlapped).
  LOAD_TILE(tile0, tpc, tcc, htc)

#pragma unroll 1
  for (int t = 0; t < kNT; ++t) {
    _Float16* __restrict__ sb = &s_e[t & 1][0];

    // ---- Stage ex -> LDS buf (frees ex for the next prefetch).
    {
      half4v* se = (half4v*)(sb + tid * kSEH);
#pragma unroll
      for (int j = 0; j < 10; ++j) {
        half4v h;
        h.x = (_Float16)ex[j].x;
        h.y = (_Float16)ex[j].y;
        h.z = (_Float16)ex[j].z;
        h.w = (_Float16)ex[j].w;
        se[j] = h;
      }
    }
    // ---- Prefetch next tile NOW: its HBM latency hides under the
    // barrier + ~2700 cyc of compute below.
    if (t + 1 < kNT) LOAD_TILE(tile0 + t + 1, tpn, tcn, htn)
    __syncthreads();  // staging of this buffer visible to all lanes

    // ---- Compute: AR warm-up 48 + emit 40 with in-place z writeback.
    float z;
    {
      float x[16];
#pragma unroll
      for (int i = 0; i < 16; ++i) x[i] = 0.f;
      float pa_[15] = {tpc[0].y, tpc[0].z, tpc[0].w, tpc[1].x, tpc[1].y,
                       tpc[1].z, tpc[1].w, tpc[2].x, tpc[2].y, tpc[2].z,
                       tpc[2].w, tpc[3].x, tpc[3].y, tpc[3].z, tpc[3].w};
      const float ca_[15] = {tcc[0].y, tcc[0].z, tcc[0].w, tcc[1].x,
                             tcc[1].y, tcc[1].z, tcc[1].w, tcc[2].x,
                             tcc[2].y, tcc[2].z, tcc[2].w, tcc[3].x,
                             tcc[3].y, tcc[3].z, tcc[3].w};
      const half4v* __restrict__ s2 =
          (const half4v*)(sb + max(tid - 2, 0) * kSEH);
      const half4v* __restrict__ s1 =
          (const half4v*)(sb + max(tid - 1, 0) * kSEH);
      const float m2 = (htc >= 2) ? 1.f : 0.f;  // pre-signal inputs -> 0
      const float m1 = (htc >= 1) ? 1.f : 0.f;
      // Warm samples 0..7: tail (32..39) of half-frame ht-2, prev taps.
#pragma unroll
      for (int j = 0; j < 2; ++j) {
        const half4v h = s2[8 + j];
        const float f_[4] = {m2 * (float)h.x, m2 * (float)h.y,
                             m2 * (float)h.z, m2 * (float)h.w};
#pragma unroll
        for (int q = 0; q < 4; ++q) {
          AR_SAMPLE(pa_, 4 * j + q, f_[q], acc)
          (void)acc;
        }
      }
      // Half-frame ht-1 uses cur-frame taps when ht is odd (one-time
      // select; masked lanes don't care).
      if (htc & 1) {
#pragma unroll
        for (int k = 0; k < 15; ++k) pa_[k] = ca_[k];
      }
      // Warm samples 8..47: half-frame ht-1 in full.
#pragma unroll
      for (int j = 0; j < 10; ++j) {
        const half4v h = s1[j];
        const float f_[4] = {m1 * (float)h.x, m1 * (float)h.y,
                             m1 * (float)h.z, m1 * (float)h.w};
#pragma unroll
        for (int q = 0; q < 4; ++q) {
          AR_SAMPLE(pa_, 8 + 4 * j + q, f_[q], acc)
          (void)acc;
        }
      }
      // Cross-wave hazard: wave-1 lanes read slots 62,63 in warm-up;
      // emit writebacks must wait for them.
      __syncthreads();
      z = 0.f;
      half4v* __restrict__ ses = (half4v*)(sb + tid * kSEH);
#pragma unroll
      for (int j = 0; j < 10; ++j) {
        const half4v h = ses[j];
        const float f_[4] = {(float)h.x, (float)h.y, (float)h.z,
                             (float)h.w};
        half4v ho;
#pragma unroll
        for (int q = 0; q < 4; ++q) {
          AR_SAMPLE(ca_, 48 + 4 * j + q, f_[q], acc)
          z = fmaf(kEmph, z, acc);
          if (q == 0) ho.x = (_Float16)z;
          if (q == 1) ho.y = (_Float16)z;
          if (q == 2) ho.z = (_Float16)z;
          if (q == 3) ho.w = (_Float16)z;
        }
        ses[j] = ho;  // in-place: own slot, read-before-write
      }
    }
    s_zend[tid] = (htc < 0 || htc >= kH) ? 0.f : z;
    __syncthreads();

    // ---- Per-output de-emph init (9-term Neumann, r = 0.97^40).
    if (tid < kEmitH) {
      float Zp = s_zend[tid + 8];
      Zp = fmaf(kR1, s_zend[tid + 7], Zp);
      Zp = fmaf(kR2, s_zend[tid + 6], Zp);
      Zp = fmaf(kR3, s_zend[tid + 5], Zp);
      Zp = fmaf(kR4, s_zend[tid + 4], Zp);
      Zp = fmaf(kR5, s_zend[tid + 3], Zp);
      Zp = fmaf(kR6, s_zend[tid + 2], Zp);
      Zp = fmaf(kR7, s_zend[tid + 1], Zp);
      Zp = fmaf(kR8, s_zend[tid + 0], Zp);
      s_zp[tid] = Zp;
    }
    __syncthreads();

    // ---- Coalesced store + correction: z += 0.97^(s+1) * Zp.
    // Lane-consecutive float4s: full 1 KB bursts per wave. These stores
    // drain under the next tile's compute (no wait is ever issued on them).
    {
      const int hbase = (tile0 + t) * kEmitH;
      const int nfr = min(kEmitH, kH - hbase);  // <=0 for phantom tiles
      const int nv4 = nfr * 10;
      vfloat4* __restrict__ ob =
          (vfloat4*)(out + (size_t)b * kL + (size_t)hbase * kHS);
#pragma unroll 1
      for (int i = tid; i < nv4; i += kThreads) {
        const int k = i / 10;  // half-frame within tile -> slot k+9
        const int j = i % 10;  // float4 within half-frame
        const half4v h = *(const half4v*)(sb + (k + kJunk) * kSEH + 4 * j);
        const float Zp = s_zp[k];
        const float ee = __builtin_exp2f(kLg97 * (float)(4 * j + 1));
        vfloat4 v;
        v.x = fmaf(ee, Zp, (float)h.x);
        v.y = fmaf(ee * 0.97f, Zp, (float)h.y);
        v.z = fmaf(ee * 0.9409f, Zp, (float)h.z);
        v.w = fmaf(ee * 0.912673f, Zp, (float)h.w);
        ob[i] = v;
      }
    }

    // ---- Rotate next-tile taps into current (ex already holds next).
    if (t + 1 < kNT) {
#pragma unroll
      for (int j = 0; j < 4; ++j) {
        tpc[j] = tpn[j];
        tcc[j] = tcn[j];
      }
      htc = htn;
    }
  }
#undef AR_SAMPLE
#undef LOAD_TILE
}

extern "C" void kernel_launch(void* const* d_in, const int* in_sizes, int n_in,
                              void* d_out, int out_size, void* d_ws,
                              size_t ws_size, hipStream_t stream) {
  const float* excit = (const float*)d_in[0];  // (B, L, 1) fp32
  const float* coef = (const float*)d_in[1];   // (B, F, 16) fp32
  float* out = (float*)d_out;                  // (B, L, 1) fp32

  dim3 grid(kCols, kB);  // 26 x 64 blocks of 128, kNT=2 tiles each
  lpc_synth_kernel<<<grid, kThreads, 0, stream>>>(excit, coef, out);
}

// Round 9
// 139.472 us; speedup vs baseline: 1.0511x; 1.0511x over previous
//
#include <hip/hip_runtime.h>

// LPC synthesis (AR(15), frame-hopped coefs) + de-emphasis IIR.
//
// R15: ASYNC LDS PIPELINE, PLAIN-BARRIER EDITION. R14 (same pipeline with
// raw s_barrier + counted vmcnt inline asm) never ran (container failed
// twice -- possibly a hang in the hand-rolled barriers, possibly infra).
// De-risk: the counted-vmcnt machinery is unnecessary HERE because the
// first barrier after the stage(t+1) issue comes after the 48-sample
// warm-up (~1800+ issue cyc) > HBM latency (~900 cyc) -- a plain
// __syncthreads (which drains vmcnt(0)) waits on an already-complete DMA.
// So: stock __syncthreads everywhere, zero inline-asm waits.
//
// Mechanism kept from the R14 design:
//  - stage tile t+1 into LDS buffer B via __builtin_amdgcn_global_load_lds
//    (async DMA, ZERO registers held across compute -- structurally immune
//    to R13's scratch-spill failure: FETCH/WRITE +25 MB symmetric) while
//    computing tile t from buffer A.
//  - fp32 staging & writeback (DMA can't convert): kills the fp16 noise
//    floor; absmax should drop 0.0156 -> ~1e-3 (Neumann 4e-4 + rho^48).
//  - LDS slot stride 44 floats (176 B): 40 data + 4 linear-DMA overlap
//    words (real, unused data; padding can't be skipped). 8-way bank
//    conflict on ds_read_b128 accepted (LDS ~6% of compute issue).
//  - DMA completion/visibility: each __syncthreads drains the issuing
//    wave's vmcnt then joins s_barrier -> cross-wave LDS visibility.
//  - sched_barrier(0) after the stage issue: compile-time fence only,
//    stops the scheduler sinking the DMA below the warm-up.
// Kept from R12: half-frame decomposition (lane = 40-sample half-frame),
// 48-sample AR warm-up (rho^48), 9-term Neumann de-emph init correction
// (r=0.97^40, residual ~4e-4), in-place z writeback + coalesced store
// phase (R8: scattered 16B/lane stores write-amplify 2.6x), pre-signal
// masking, fmaf(-a,..) neg-modifier tap folding. R3: no runtime-indexed
// per-lane arrays.

namespace {
constexpr int kFS = 80;         // frame shift
constexpr int kHS = 40;         // samples per half-frame
constexpr int kF = 3000;        // frames per batch
constexpr int kH = 2 * kF;      // 6000 half-frames per batch
constexpr int kL = kFS * kF;    // 240000
constexpr int kOrder = 16;
constexpr int kB = 64;
constexpr float kEmph = 0.97f;
constexpr int kThreads = 128;   // 2 waves/block
constexpr int kJunk = 9;        // 9-term correction needs 9 lead lanes
constexpr int kEmitH = kThreads - kJunk;  // 119 half-frames per tile
constexpr int kSlotF = 44;      // floats per LDS slot (176 B)
constexpr int kBufF = kThreads * kSlotF;    // 5632 floats = 22528 B
constexpr int kIss = kBufF / (2 * 64 * 4);  // 11 DMA issues per wave
constexpr int kNT = 3;          // tiles per block
constexpr int kCols = 17;       // 17*3 = 51 tiles exactly, no phantoms
constexpr float kLg97 = -4.3943347e-2f;  // log2(0.97)
// powers of r = 0.97^40
constexpr float kR1 = 0.2957118f;
constexpr float kR2 = 0.08744547f;
constexpr float kR3 = 0.02585867f;
constexpr float kR4 = 0.00764671f;
constexpr float kR5 = 0.00226126f;
constexpr float kR6 = 6.6867e-4f;
constexpr float kR7 = 1.9773e-4f;
constexpr float kR8 = 5.8472e-5f;

typedef float vfloat4 __attribute__((ext_vector_type(4)));

// Issue the 11 per-wave DMA ops staging one tile's excitation into LDS.
// HW semantics: LDS dest is wave-uniform base + lane*16; the per-lane
// GLOBAL address is chosen so the linear LDS image is [slot][44 floats]
// with slot s holding half-frame clamp(tile*kEmitH + s - kJunk).
__device__ __forceinline__ void stage_tile(const float* __restrict__ ebase,
                                           float* sbuf, int tile, int wv,
                                           int ln) {
#pragma unroll
  for (int i = 0; i < kIss; ++i) {
    const int c = wv * kIss + i;  // 1 KB chunk index (wave-uniform)
    const int W4 = c * 64 + ln;   // flat float4 index in buffer
    const int s = W4 / 11;        // LDS slot (0..127); 11 float4s/slot
    const int o4 = W4 - s * 11;   // float4 within slot
    const int ht = tile * kEmitH + s - kJunk;
    const int hc = min(max(ht, 0), kH - 1);
    const int fidx = min(hc * kHS + o4 * 4, kL - 4);
    __builtin_amdgcn_global_load_lds(
        (const __attribute__((address_space(1))) float*)(ebase + fidx),
        (__attribute__((address_space(3))) float*)(sbuf + (c << 8)), 16, 0,
        0);
  }
}
}  // namespace

// One AR sample; 3 partial accumulators keep the cross-sample critical
// path at 1 fma + 1 add (8 cyc). Taps consumed as -A[k] via the fmaf
// neg source modifier (zero cost).
#define AR_SAMPLE(A, s, e_in, ACC)                                         \
  float ACC;                                                               \
  {                                                                        \
    float t0 = (e_in);                                                     \
    t0 = fmaf(-A[14], x[((s)-15) & 15], t0);                               \
    t0 = fmaf(-A[13], x[((s)-14) & 15], t0);                               \
    t0 = fmaf(-A[12], x[((s)-13) & 15], t0);                               \
    t0 = fmaf(-A[11], x[((s)-12) & 15], t0);                               \
    t0 = fmaf(-A[10], x[((s)-11) & 15], t0);                               \
    float t1 = -A[9] * x[((s)-10) & 15];                                   \
    t1 = fmaf(-A[8], x[((s)-9) & 15], t1);                                 \
    t1 = fmaf(-A[7], x[((s)-8) & 15], t1);                                 \
    t1 = fmaf(-A[6], x[((s)-7) & 15], t1);                                 \
    t1 = fmaf(-A[5], x[((s)-6) & 15], t1);                                 \
    float t2 = -A[4] * x[((s)-5) & 15];                                    \
    t2 = fmaf(-A[3], x[((s)-4) & 15], t2);                                 \
    t2 = fmaf(-A[2], x[((s)-3) & 15], t2);                                 \
    t2 = fmaf(-A[1], x[((s)-2) & 15], t2);                                 \
    const float t01 = t0 + t1;               /* off critical path */       \
    t2 = fmaf(-A[0], x[((s)-1) & 15], t2);   /* critical: 1 fma */         \
    ACC = t01 + t2;                          /* + 1 add */                 \
    x[(s)&15] = ACC;                                                       \
  }

__global__ __launch_bounds__(kThreads) void lpc_synth_kernel(
    const float* __restrict__ excit, const float* __restrict__ coef,
    float* __restrict__ out) {
  __shared__ float s_ex[2 * kBufF];   // 45056 B: double-buffered tiles
  __shared__ float s_zend[kThreads];  //   512 B: per-lane zh
  __shared__ float s_zp[kThreads];    //   512 B: per-output Zp

  const int tid = threadIdx.x;
  const int ln = tid & 63;
  const int wv = tid >> 6;
  const int b = blockIdx.y;
  const int tile0 = blockIdx.x * kNT;

  const float* __restrict__ ebase = excit + (size_t)b * kL;
  const float* __restrict__ cbase = coef + (size_t)b * kF * kOrder;
  float* __restrict__ outb = out + (size_t)b * kL;

  // ---- Prologue: stage tile0 into buffer 0 (ramp; not overlapped).
  stage_tile(ebase, s_ex, tile0, wv, ln);

#pragma unroll 1
  for (int t = 0; t < kNT; ++t) {
    const int tile = tile0 + t;
    float* __restrict__ sb = s_ex + (t & 1) * kBufF;
    float* __restrict__ sn = s_ex + ((t + 1) & 1) * kBufF;

    // stage(t) complete + cross-wave visible; also the WAR fence: the
    // buffer stage(t+1) will write was last read by store(t-1).
    __syncthreads();

    // ---- Issue async stage of tile t+1 (flies under the warm-up).
    if (t + 1 < kNT) {
      stage_tile(ebase, sn, tile + 1, wv, ln);
      __builtin_amdgcn_sched_barrier(0);  // don't sink DMA below compute
    }

    const int ht = tile * kEmitH + tid - kJunk;
    const int hc = min(max(ht, 0), kH - 1);
    const int hw = min(max(ht - 2, 0), kH - 1);

    // ---- Tap loads (compiler schedules/waits them as needed).
    const vfloat4* __restrict__ cp_ =
        (const vfloat4*)(cbase + (size_t)(hw >> 1) * kOrder);
    const vfloat4* __restrict__ cc_ =
        (const vfloat4*)(cbase + (size_t)(hc >> 1) * kOrder);
    const vfloat4 p0 = cp_[0], p1 = cp_[1], p2 = cp_[2], p3 = cp_[3];
    const vfloat4 q0 = cc_[0], q1 = cc_[1], q2 = cc_[2], q3 = cc_[3];

    // ---- Compute: AR warm-up 48 samples.
    float x[16];
#pragma unroll
    for (int i = 0; i < 16; ++i) x[i] = 0.f;
    float pa_[15] = {p0.y, p0.z, p0.w, p1.x, p1.y, p1.z, p1.w, p2.x,
                     p2.y, p2.z, p2.w, p3.x, p3.y, p3.z, p3.w};
    const float ca_[15] = {q0.y, q0.z, q0.w, q1.x, q1.y, q1.z, q1.w, q2.x,
                           q2.y, q2.z, q2.w, q3.x, q3.y, q3.z, q3.w};
    {
      const float* __restrict__ s2 = sb + max(tid - 2, 0) * kSlotF;
      const float* __restrict__ s1 = sb + max(tid - 1, 0) * kSlotF;
      const float m2 = (ht >= 2) ? 1.f : 0.f;  // pre-signal inputs -> 0
      const float m1 = (ht >= 1) ? 1.f : 0.f;
      // Warm 0..7: tail (words 32..39) of half-frame ht-2, prev taps.
#pragma unroll
      for (int j = 8; j < 10; ++j) {
        const vfloat4 v = *(const vfloat4*)(s2 + 4 * j);
        const float f_[4] = {m2 * v.x, m2 * v.y, m2 * v.z, m2 * v.w};
#pragma unroll
        for (int q = 0; q < 4; ++q) {
          AR_SAMPLE(pa_, 4 * (j - 8) + q, f_[q], acc)
          (void)acc;
        }
      }
      // Half-frame ht-1 uses cur-frame taps when ht odd (one-time select).
      if (ht & 1) {
#pragma unroll
        for (int k = 0; k < 15; ++k) pa_[k] = ca_[k];
      }
      // Warm 8..47: half-frame ht-1 in full.
#pragma unroll
      for (int j = 0; j < 10; ++j) {
        const vfloat4 v = *(const vfloat4*)(s1 + 4 * j);
        const float f_[4] = {m1 * v.x, m1 * v.y, m1 * v.z, m1 * v.w};
#pragma unroll
        for (int q = 0; q < 4; ++q) {
          AR_SAMPLE(pa_, 8 + 4 * j + q, f_[q], acc)
          (void)acc;
        }
      }
    }
    // Warm-read -> emit-writeback hazard. The implied vmcnt(0) drain also
    // waits stage(t+1), which the ~1800-cyc warm-up has already covered.
    __syncthreads();

    // ---- Emit: AR + half-frame-local z, fp32 writeback in place
    // (own slot, read-before-write within each j).
    float z = 0.f;
    {
      float* __restrict__ so = sb + tid * kSlotF;
#pragma unroll
      for (int j = 0; j < 10; ++j) {
        const vfloat4 v = *(const vfloat4*)(so + 4 * j);
        vfloat4 zv;
#pragma unroll
        for (int q = 0; q < 4; ++q) {
          AR_SAMPLE(ca_, 48 + 4 * j + q, v[q], acc)
          z = fmaf(kEmph, z, acc);
          if (q == 0) zv.x = z;
          if (q == 1) zv.y = z;
          if (q == 2) zv.z = z;
          if (q == 3) zv.w = z;
        }
        *(vfloat4*)(so + 4 * j) = zv;
      }
    }
    s_zend[tid] = (ht < 0 || ht >= kH) ? 0.f : z;
    __syncthreads();  // writebacks + zend visible

    // ---- Per-output de-emph init (9-term Neumann, r = 0.97^40).
    if (tid < kEmitH) {
      float Zp = s_zend[tid + 8];
      Zp = fmaf(kR1, s_zend[tid + 7], Zp);
      Zp = fmaf(kR2, s_zend[tid + 6], Zp);
      Zp = fmaf(kR3, s_zend[tid + 5], Zp);
      Zp = fmaf(kR4, s_zend[tid + 4], Zp);
      Zp = fmaf(kR5, s_zend[tid + 3], Zp);
      Zp = fmaf(kR6, s_zend[tid + 2], Zp);
      Zp = fmaf(kR7, s_zend[tid + 1], Zp);
      Zp = fmaf(kR8, s_zend[tid + 0], Zp);
      s_zp[tid] = Zp;
    }
    __syncthreads();  // s_zp visible

    // ---- Coalesced store + correction: z += 0.97^(s+1) * Zp.
    // Lane-consecutive float4s: full 1 KB bursts per wave (R8 lesson).
    // Stores are fire-and-forget; they drain under the next tile.
    {
      const int hbase = tile * kEmitH;
      const int nv4 = min(kEmitH, kH - hbase) * 10;
      vfloat4* __restrict__ ob = (vfloat4*)(outb + (size_t)hbase * kHS);
#pragma unroll 1
      for (int i = tid; i < nv4; i += kThreads) {
        const int k = i / 10;  // half-frame within tile -> slot k+9
        const int j = i - 10 * k;
        const vfloat4 h =
            *(const vfloat4*)(sb + (k + kJunk) * kSlotF + 4 * j);
        const float Zp = s_zp[k];
        const float ee = __builtin_exp2f(kLg97 * (float)(4 * j + 1));
        vfloat4 v;
        v.x = fmaf(ee, Zp, h.x);
        v.y = fmaf(ee * 0.97f, Zp, h.y);
        v.z = fmaf(ee * 0.9409f, Zp, h.z);
        v.w = fmaf(ee * 0.912673f, Zp, h.w);
        ob[i] = v;
      }
    }
    // Loop back: the next iteration's top __syncthreads is the WAR fence
    // before stage(t+2) overwrites this tile's buffer.
  }
}
#undef AR_SAMPLE

extern "C" void kernel_launch(void* const* d_in, const int* in_sizes, int n_in,
                              void* d_out, int out_size, void* d_ws,
                              size_t ws_size, hipStream_t stream) {
  const float* excit = (const float*)d_in[0];  // (B, L, 1) fp32
  const float* coef = (const float*)d_in[1];   // (B, F, 16) fp32
  float* out = (float*)d_out;                  // (B, L, 1) fp32

  dim3 grid(kCols, kB);  // 17 x 64 blocks of 128, kNT=3 tiles each
  lpc_synth_kernel<<<grid, kThreads, 0, stream>>>(excit, coef, out);
}

// Round 10
// 136.808 us; speedup vs baseline: 1.0716x; 1.0195x over previous
//
#include <hip/hip_runtime.h>

// LPC synthesis (AR(15), frame-hopped coefs) + de-emphasis IIR.
//
// R16: GLOBAL-DIRECT READS + LDS ONLY FOR OUTPUT COALESCING.
// Session evidence: R12 (12.3 KB LDS, 13 blocks/CU, plain barriers) = 41 us
// beats both pipeline attempts (R13 reg-prefetch spilled: 62 us; R15 async
// DMA + __syncthreads drained the previous tile's stores every iteration
// at 3 blocks/CU: 58 us). Occupancy + short phase chains win here.
// This round deletes the excit LDS staging entirely:
//  - warm-up (48) and emit (40) excit read straight from global as float4.
//    NOT the R7 failure: R7 re-read 4x over a 640 KB/CU footprint; here
//    2.2x over 22.5 KB/wave within a ~2000-cyc window -> L1/L2-resident.
//  - LDS keeps only the z output buffer (R8 proved scattered 16B/lane
//    stores write-amplify 2.6x at occupancy; R9's LDS-coalesced store
//    measured WRITE = 60 MB = ideal): 128 slots x 42 floats (168 B,
//    bank stride 10 -> 4-way on b64 ~ free) = 21504 B -> 7 blocks/CU,
//    14 waves/CU residency (~2x R12), 2 barriers instead of 4.
//  - fp32 z end-to-end: absmax floor 0.0078 (R15-measured; Neumann 4e-4
//    + rho^48 AR truncation) vs threshold 0.0456.
// Kept from R12: half-frame decomposition (lane = 40-sample half-frame),
// 48-sample AR warm-up, tap select at the odd/even half-frame boundary,
// 9-term Neumann de-emph init (r = 0.97^40), pre-signal masking,
// fmaf(-a,..) neg-modifier tap folding, hoisted tap loads.
// R3/R13 lesson: no big live register arrays -- global reads are consumed
// in place (compiler keeps a few in flight).

namespace {
constexpr int kHS = 40;         // samples per half-frame
constexpr int kF = 3000;        // frames per batch
constexpr int kH = 2 * kF;      // 6000 half-frames per batch
constexpr int kL = kHS * kH;    // 240000
constexpr int kOrder = 16;
constexpr int kB = 64;
constexpr float kEmph = 0.97f;
constexpr int kThreads = 128;   // 2 waves/block
constexpr int kJunk = 9;        // 9-term correction needs 9 lead lanes
constexpr int kEmitH = kThreads - kJunk;  // 119 half-frames per block
constexpr int kSlotF = 42;      // z-slot stride in floats (168 B)
constexpr int kCols = 51;       // ceil(6000/119)
constexpr float kLg97 = -4.3943347e-2f;  // log2(0.97)
// powers of r = 0.97^40
constexpr float kR1 = 0.2957118f;
constexpr float kR2 = 0.08744547f;
constexpr float kR3 = 0.02585867f;
constexpr float kR4 = 0.00764671f;
constexpr float kR5 = 0.00226126f;
constexpr float kR6 = 6.6867e-4f;
constexpr float kR7 = 1.9773e-4f;
constexpr float kR8 = 5.8472e-5f;

typedef float vfloat4 __attribute__((ext_vector_type(4)));
typedef float vfloat2 __attribute__((ext_vector_type(2)));
}  // namespace

// One AR sample; 3 partial accumulators keep the cross-sample critical
// path at 1 fma + 1 add (8 cyc) vs ~38 cyc of issue. Taps consumed as
// -A[k] via the fmaf neg source modifier (zero cost).
#define AR_SAMPLE(A, s, e_in, ACC)                                         \
  float ACC;                                                               \
  {                                                                        \
    float t0 = (e_in);                                                     \
    t0 = fmaf(-A[14], x[((s)-15) & 15], t0);                               \
    t0 = fmaf(-A[13], x[((s)-14) & 15], t0);                               \
    t0 = fmaf(-A[12], x[((s)-13) & 15], t0);                               \
    t0 = fmaf(-A[11], x[((s)-12) & 15], t0);                               \
    t0 = fmaf(-A[10], x[((s)-11) & 15], t0);                               \
    float t1 = -A[9] * x[((s)-10) & 15];                                   \
    t1 = fmaf(-A[8], x[((s)-9) & 15], t1);                                 \
    t1 = fmaf(-A[7], x[((s)-8) & 15], t1);                                 \
    t1 = fmaf(-A[6], x[((s)-7) & 15], t1);                                 \
    t1 = fmaf(-A[5], x[((s)-6) & 15], t1);                                 \
    float t2 = -A[4] * x[((s)-5) & 15];                                    \
    t2 = fmaf(-A[3], x[((s)-4) & 15], t2);                                 \
    t2 = fmaf(-A[2], x[((s)-3) & 15], t2);                                 \
    t2 = fmaf(-A[1], x[((s)-2) & 15], t2);                                 \
    const float t01 = t0 + t1;               /* off critical path */       \
    t2 = fmaf(-A[0], x[((s)-1) & 15], t2);   /* critical: 1 fma */         \
    ACC = t01 + t2;                          /* + 1 add */                 \
    x[(s)&15] = ACC;                                                       \
  }

__global__ __launch_bounds__(kThreads) void lpc_synth_kernel(
    const float* __restrict__ excit, const float* __restrict__ coef,
    float* __restrict__ out) {
  __shared__ float s_z[kThreads * kSlotF];  // 21504 B: fp32 z per slot
  __shared__ float s_zend[kThreads];        //   512 B: per-lane zh
  __shared__ float s_zp[kThreads];          //   512 B: per-output Zp

  const int tid = threadIdx.x;
  const int b = blockIdx.y;
  const int hbase = blockIdx.x * kEmitH;
  const int ht = hbase + tid - kJunk;  // half-frame this lane emits
  const int hc = min(max(ht, 0), kH - 1);
  const int h1 = min(max(ht - 1, 0), kH - 1);
  const int h2 = min(max(ht - 2, 0), kH - 1);

  const float* __restrict__ ebase = excit + (size_t)b * kL;
  const float* __restrict__ cbase = coef + (size_t)b * kF * kOrder;

  // ---- Hoisted tap loads (prev frame for warm-up, cur frame for emit);
  // their latency hides under the warm-up's own excit loads.
  const vfloat4* __restrict__ cp_ =
      (const vfloat4*)(cbase + (size_t)(h2 >> 1) * kOrder);
  const vfloat4* __restrict__ cc_ =
      (const vfloat4*)(cbase + (size_t)(hc >> 1) * kOrder);
  const vfloat4 p0 = cp_[0], p1 = cp_[1], p2 = cp_[2], p3 = cp_[3];
  const vfloat4 q0 = cc_[0], q1 = cc_[1], q2 = cc_[2], q3 = cc_[3];

  float pa_[15] = {p0.y, p0.z, p0.w, p1.x, p1.y, p1.z, p1.w, p2.x,
                   p2.y, p2.z, p2.w, p3.x, p3.y, p3.z, p3.w};
  const float ca_[15] = {q0.y, q0.z, q0.w, q1.x, q1.y, q1.z, q1.w, q2.x,
                         q2.y, q2.z, q2.w, q3.x, q3.y, q3.z, q3.w};

  // Ring buffer of last 16 y-samples; local sample counter s = 0..87
  // (warm 0..47, emit 48..87). Compile-time indexed -> VGPRs.
  float x[16];
#pragma unroll
  for (int i = 0; i < 16; ++i) x[i] = 0.f;

  // ---- Warm-up 48 samples, excit straight from global (float4s,
  // consumed in place; compiler pipelines the independent loads).
  {
    const vfloat4* __restrict__ e2 = (const vfloat4*)(ebase + h2 * kHS);
    const vfloat4* __restrict__ e1 = (const vfloat4*)(ebase + h1 * kHS);
    const float m2 = (ht >= 2) ? 1.f : 0.f;  // pre-signal inputs -> 0
    const float m1 = (ht >= 1) ? 1.f : 0.f;
    // Samples 0..7: tail (words 32..39) of half-frame ht-2, prev taps.
#pragma unroll
    for (int j = 8; j < 10; ++j) {
      const vfloat4 v = e2[j];
      const float f_[4] = {m2 * v.x, m2 * v.y, m2 * v.z, m2 * v.w};
#pragma unroll
      for (int q = 0; q < 4; ++q) {
        AR_SAMPLE(pa_, 4 * (j - 8) + q, f_[q], acc)
        (void)acc;
      }
    }
    // Half-frame ht-1 belongs to frame ht>>1 when ht is odd: one-time
    // tap select (masked lanes don't care).
    if (ht & 1) {
#pragma unroll
      for (int k = 0; k < 15; ++k) pa_[k] = ca_[k];
    }
    // Samples 8..47: half-frame ht-1 in full.
#pragma unroll
    for (int j = 0; j < 10; ++j) {
      const vfloat4 v = e1[j];
      const float f_[4] = {m1 * v.x, m1 * v.y, m1 * v.z, m1 * v.w};
#pragma unroll
      for (int q = 0; q < 4; ++q) {
        AR_SAMPLE(pa_, 8 + 4 * j + q, f_[q], acc)
        (void)acc;
      }
    }
  }

  // ---- Emit 40 samples: excit from global, z (fp32) into own LDS slot.
  float z = 0.f;
  {
    const vfloat4* __restrict__ ee_ = (const vfloat4*)(ebase + hc * kHS);
    float* __restrict__ so = s_z + tid * kSlotF;
#pragma unroll
    for (int j = 0; j < 10; ++j) {
      const vfloat4 v = ee_[j];
      float zv[4];
#pragma unroll
      for (int q = 0; q < 4; ++q) {
        AR_SAMPLE(ca_, 48 + 4 * j + q, v[q], acc)
        z = fmaf(kEmph, z, acc);  // de-emph over this half-frame only
        zv[q] = z;
      }
      vfloat2 a, c;
      a.x = zv[0]; a.y = zv[1];
      c.x = zv[2]; c.y = zv[3];
      *(vfloat2*)(so + 4 * j) = a;      // b64 writes, stride 42 words:
      *(vfloat2*)(so + 4 * j + 2) = c;  // 4-way bank alias ~ free (m136)
    }
  }
  // zh = 0 outside the signal so correction terms vanish automatically.
  s_zend[tid] = (ht < 0 || ht >= kH) ? 0.f : z;
  __syncthreads();

  // ---- Per-output de-emph init (9-term Neumann, r = 0.97^40):
  // output k (block-local, lane k+9): Zp = sum_{i=1..9} r^(i-1)*zh[k+9-i].
  if (tid < kEmitH) {
    float Zp = s_zend[tid + 8];
    Zp = fmaf(kR1, s_zend[tid + 7], Zp);
    Zp = fmaf(kR2, s_zend[tid + 6], Zp);
    Zp = fmaf(kR3, s_zend[tid + 5], Zp);
    Zp = fmaf(kR4, s_zend[tid + 4], Zp);
    Zp = fmaf(kR5, s_zend[tid + 3], Zp);
    Zp = fmaf(kR6, s_zend[tid + 2], Zp);
    Zp = fmaf(kR7, s_zend[tid + 1], Zp);
    Zp = fmaf(kR8, s_zend[tid + 0], Zp);
    s_zp[tid] = Zp;
  }
  __syncthreads();

  // ---- Coalesced store + correction: z_exact(s) = z_loc(s) + 0.97^(s+1)*Zp.
  // Lane-consecutive float4s: full 1 KB bursts per wave (R8/R9 lesson).
  {
    const int nv4 = min(kEmitH, kH - hbase) * 10;
    vfloat4* __restrict__ ob =
        (vfloat4*)(out + (size_t)b * kL + (size_t)hbase * kHS);
#pragma unroll 1
    for (int i = tid; i < nv4; i += kThreads) {
      const int k = i / 10;  // half-frame within block -> z slot k+9
      const int j = i - 10 * k;
      const float* sp = s_z + (k + kJunk) * kSlotF + 4 * j;
      const vfloat2 h0 = *(const vfloat2*)sp;
      const vfloat2 h1v = *(const vfloat2*)(sp + 2);
      const float Zp = s_zp[k];
      const float ee = __builtin_exp2f(kLg97 * (float)(4 * j + 1));
      vfloat4 v;
      v.x = fmaf(ee, Zp, h0.x);
      v.y = fmaf(ee * 0.97f, Zp, h0.y);
      v.z = fmaf(ee * 0.9409f, Zp, h1v.x);
      v.w = fmaf(ee * 0.912673f, Zp, h1v.y);
      ob[i] = v;
    }
  }
}
#undef AR_SAMPLE

extern "C" void kernel_launch(void* const* d_in, const int* in_sizes, int n_in,
                              void* d_out, int out_size, void* d_ws,
                              size_t ws_size, hipStream_t stream) {
  const float* excit = (const float*)d_in[0];  // (B, L, 1) fp32
  const float* coef = (const float*)d_in[1];   // (B, F, 16) fp32
  float* out = (float*)d_out;                  // (B, L, 1) fp32

  dim3 grid(kCols, kB);  // 51 x 64 blocks of 128
  lpc_synth_kernel<<<grid, kThreads, 0, stream>>>(excit, coef, out);
}

// Round 11
// 124.772 us; speedup vs baseline: 1.1749x; 1.0965x over previous
//
#include <hip/hip_runtime.h>

// LPC synthesis (AR(15), frame-hopped coefs) + de-emphasis IIR.
//
// R17: COALESCED COOPERATIVE STAGING (R12 structure, fixed input path).
// Session evidence: R12 (stage-once in LDS, 4 short phases, plain
// barriers) = ~41 us is the best structure; R13 (reg prefetch) spilled;
// R15 (async DMA) drained stores at 3 blocks/CU; R16 (global-direct
// reads) paid the scattered-VMEM tax twice: per-lane 160B-stride dwordx4
// = 64 cache lines per instruction (4x transactions), FETCH 37->56 MB,
// 51.5 us. The ONE phase never coalesced until now is input staging:
// a block's input is contiguous (half-frames hbase-11..hbase+118, 130
// slots x 40 samples = 20.8 KB), so stage it like the R9 store phase:
// flat i = tid + p*128, lane-consecutive float4s -> every wave load is a
// full 1 KB burst (16 lines/instr, the minimum).
//  - LDS layout [130 slots][44 words]: 176 B stride is 16B-aligned for
//    ds_read_b128 and 2-lanes/bank (free, m136) vs R12's 119-380K
//    conflict cycles at stride 84/42.
//  - fp32 staging + fp32 z (absmax 0.0078, 2.9x margin under 0.0456).
//  - z written back IN PLACE into the lane's input slot (tid+2) during
//    emit (same-lane RAW: read v before write) -> no separate z buffer;
//    LDS total 23.9 KB -> 6 blocks/CU, ~12 waves resident.
// Kept from R12: half-frame per lane, 48-sample AR warm-up (rho^48),
// odd/even tap select, 9-term Neumann de-emph init (r=0.97^40, residual
// ~4e-4), pre-signal masking, fmaf(-a,..) neg-modifier folding, hoisted
// tap loads, 4 plain barriers, coalesced store phase (R8: scattered
// stores write-amplify 2.6x). R3/R13: no big live register arrays.

namespace {
constexpr int kHS = 40;         // samples per half-frame
constexpr int kF = 3000;        // frames per batch
constexpr int kH = 2 * kF;      // 6000 half-frames per batch
constexpr int kL = kHS * kH;    // 240000
constexpr int kL4 = kL / 4;     // 60000 float4s per batch row
constexpr int kOrder = 16;
constexpr int kB = 64;
constexpr float kEmph = 0.97f;
constexpr int kThreads = 128;   // 2 waves/block
constexpr int kJunk = 9;        // 9-term correction needs 9 lead lanes
constexpr int kEmitH = kThreads - kJunk;  // 119 half-frames per block
constexpr int kInSlots = 130;   // input half-frames: hbase-11..hbase+118
constexpr int kSlotW = 44;      // words per LDS slot (176 B, 16B-aligned)
constexpr int kIn4 = kInSlots * 10;  // 1300 float4s staged per block
constexpr int kCols = 51;       // ceil(6000/119)
constexpr float kLg97 = -4.3943347e-2f;  // log2(0.97)
// powers of r = 0.97^40
constexpr float kR1 = 0.2957118f;
constexpr float kR2 = 0.08744547f;
constexpr float kR3 = 0.02585867f;
constexpr float kR4 = 0.00764671f;
constexpr float kR5 = 0.00226126f;
constexpr float kR6 = 6.6867e-4f;
constexpr float kR7 = 1.9773e-4f;
constexpr float kR8 = 5.8472e-5f;

typedef float vfloat4 __attribute__((ext_vector_type(4)));
}  // namespace

// One AR sample; 3 partial accumulators keep the cross-sample critical
// path at 1 fma + 1 add (8 cyc) vs ~38 cyc of issue. Taps consumed as
// -A[k] via the fmaf neg source modifier (zero cost).
#define AR_SAMPLE(A, s, e_in, ACC)                                         \
  float ACC;                                                               \
  {                                                                        \
    float t0 = (e_in);                                                     \
    t0 = fmaf(-A[14], x[((s)-15) & 15], t0);                               \
    t0 = fmaf(-A[13], x[((s)-14) & 15], t0);                               \
    t0 = fmaf(-A[12], x[((s)-13) & 15], t0);                               \
    t0 = fmaf(-A[11], x[((s)-12) & 15], t0);                               \
    t0 = fmaf(-A[10], x[((s)-11) & 15], t0);                               \
    float t1 = -A[9] * x[((s)-10) & 15];                                   \
    t1 = fmaf(-A[8], x[((s)-9) & 15], t1);                                 \
    t1 = fmaf(-A[7], x[((s)-8) & 15], t1);                                 \
    t1 = fmaf(-A[6], x[((s)-7) & 15], t1);                                 \
    t1 = fmaf(-A[5], x[((s)-6) & 15], t1);                                 \
    float t2 = -A[4] * x[((s)-5) & 15];                                    \
    t2 = fmaf(-A[3], x[((s)-4) & 15], t2);                                 \
    t2 = fmaf(-A[2], x[((s)-3) & 15], t2);                                 \
    t2 = fmaf(-A[1], x[((s)-2) & 15], t2);                                 \
    const float t01 = t0 + t1;               /* off critical path */       \
    t2 = fmaf(-A[0], x[((s)-1) & 15], t2);   /* critical: 1 fma */         \
    ACC = t01 + t2;                          /* + 1 add */                 \
    x[(s)&15] = ACC;                                                       \
  }

__global__ __launch_bounds__(kThreads) void lpc_synth_kernel(
    const float* __restrict__ excit, const float* __restrict__ coef,
    float* __restrict__ out) {
  __shared__ float s_x[kInSlots * kSlotW];  // 22880 B: input, then z
  __shared__ float s_zend[kThreads];        //   512 B: per-lane zh
  __shared__ float s_zp[kThreads];          //   512 B: per-output Zp

  const int tid = threadIdx.x;
  const int b = blockIdx.y;
  const int hbase = blockIdx.x * kEmitH;
  const int ht = hbase + tid - kJunk;  // half-frame this lane emits
  // Input-slot map: inSlot(h) = h - hbase + 11; lane's emit slot = tid+2.

  const float* __restrict__ ebase = excit + (size_t)b * kL;
  const float* __restrict__ cbase = coef + (size_t)b * kF * kOrder;

  // ---- Hoisted tap loads (prev frame for warm-up, cur frame for emit);
  // latency hides under the staging burst + barrier.
  {
  }
  const int hcT = min(max(ht, 0), kH - 1);
  const int hwT = min(max(ht - 2, 0), kH - 1);
  const vfloat4* __restrict__ cp_ =
      (const vfloat4*)(cbase + (size_t)(hwT >> 1) * kOrder);
  const vfloat4* __restrict__ cc_ =
      (const vfloat4*)(cbase + (size_t)(hcT >> 1) * kOrder);
  const vfloat4 p0 = cp_[0], p1 = cp_[1], p2 = cp_[2], p3 = cp_[3];
  const vfloat4 q0 = cc_[0], q1 = cc_[1], q2 = cc_[2], q3 = cc_[3];

  // ---- Cooperative coalesced staging: lane-consecutive float4s (full
  // 1 KB bursts per wave), written to the padded [slot][44] LDS layout.
  // Clamped flat indices at batch edges read junk that is masked or
  // never stored (pre-signal mask / junk-lane zend=0 / nv4 store bound).
  {
    const vfloat4* __restrict__ eg = (const vfloat4*)ebase;
    const int base4 = (hbase - 11) * 10;  // float4 index of slot0 word0
#pragma unroll
    for (int p = 0; p < 10; ++p) {
      const int i = tid + p * kThreads;
      const int g4 = min(max(base4 + i, 0), kL4 - 1);
      const vfloat4 v = eg[g4];
      const int slot = i / 10;
      const int o = i - slot * 10;
      *(vfloat4*)(s_x + slot * kSlotW + o * 4) = v;
    }
    if (tid < kIn4 - 10 * kThreads) {  // tail: 20 float4s
      const int i = 10 * kThreads + tid;
      const int g4 = min(max(base4 + i, 0), kL4 - 1);
      const vfloat4 v = eg[g4];
      const int slot = i / 10;
      const int o = i - slot * 10;
      *(vfloat4*)(s_x + slot * kSlotW + o * 4) = v;
    }
  }
  __syncthreads();

  // Ring buffer of last 16 y-samples; local sample counter s = 0..87
  // (warm 0..47, emit 48..87). Compile-time indexed -> VGPRs.
  float x[16];
#pragma unroll
  for (int i = 0; i < 16; ++i) x[i] = 0.f;

  float pa_[15] = {p0.y, p0.z, p0.w, p1.x, p1.y, p1.z, p1.w, p2.x,
                   p2.y, p2.z, p2.w, p3.x, p3.y, p3.z, p3.w};
  const float ca_[15] = {q0.y, q0.z, q0.w, q1.x, q1.y, q1.z, q1.w, q2.x,
                         q2.y, q2.z, q2.w, q3.x, q3.y, q3.z, q3.w};

  // ---- Warm-up 48 samples from LDS (slots tid, tid+1).
  {
    const float* __restrict__ s2 = s_x + tid * kSlotW;        // ht-2
    const float* __restrict__ s1 = s_x + (tid + 1) * kSlotW;  // ht-1
    const float m2 = (ht >= 2) ? 1.f : 0.f;  // pre-signal inputs -> 0
    const float m1 = (ht >= 1) ? 1.f : 0.f;
    // Samples 0..7: tail (words 32..39) of half-frame ht-2, prev taps.
#pragma unroll
    for (int j = 8; j < 10; ++j) {
      const vfloat4 v = *(const vfloat4*)(s2 + 4 * j);
      const float f_[4] = {m2 * v.x, m2 * v.y, m2 * v.z, m2 * v.w};
#pragma unroll
      for (int q = 0; q < 4; ++q) {
        AR_SAMPLE(pa_, 4 * (j - 8) + q, f_[q], acc)
        (void)acc;
      }
    }
    // Half-frame ht-1 belongs to the emit frame when ht is odd: one-time
    // tap select (masked lanes don't care).
    if (ht & 1) {
#pragma unroll
      for (int k = 0; k < 15; ++k) pa_[k] = ca_[k];
    }
    // Samples 8..47: half-frame ht-1 in full.
#pragma unroll
    for (int j = 0; j < 10; ++j) {
      const vfloat4 v = *(const vfloat4*)(s1 + 4 * j);
      const float f_[4] = {m1 * v.x, m1 * v.y, m1 * v.z, m1 * v.w};
#pragma unroll
      for (int q = 0; q < 4; ++q) {
        AR_SAMPLE(pa_, 8 + 4 * j + q, f_[q], acc)
        (void)acc;
      }
    }
  }
  // Warm-up reads slots tid,tid+1 which other lanes' emit writebacks
  // (slots tid+2) overwrite -> fence.
  __syncthreads();

  // ---- Emit 40 samples: input from own slot (tid+2), z (fp32) written
  // back IN PLACE (read v before write; no cross-lane access in emit).
  float z = 0.f;
  {
    float* __restrict__ so = s_x + (tid + 2) * kSlotW;
#pragma unroll
    for (int j = 0; j < 10; ++j) {
      const vfloat4 v = *(const vfloat4*)(so + 4 * j);
      vfloat4 zv;
#pragma unroll
      for (int q = 0; q < 4; ++q) {
        AR_SAMPLE(ca_, 48 + 4 * j + q, v[q], acc)
        z = fmaf(kEmph, z, acc);  // de-emph over this half-frame only
        if (q == 0) zv.x = z;
        if (q == 1) zv.y = z;
        if (q == 2) zv.z = z;
        if (q == 3) zv.w = z;
      }
      *(vfloat4*)(so + 4 * j) = zv;
    }
  }
  // zh = 0 outside the signal so correction terms vanish automatically.
  s_zend[tid] = (ht < 0 || ht >= kH) ? 0.f : z;
  __syncthreads();

  // ---- Per-output de-emph init (9-term Neumann, r = 0.97^40):
  // output k (block-local, lane k+9): Zp = sum_{i=1..9} r^(i-1)*zh[k+9-i].
  if (tid < kEmitH) {
    float Zp = s_zend[tid + 8];
    Zp = fmaf(kR1, s_zend[tid + 7], Zp);
    Zp = fmaf(kR2, s_zend[tid + 6], Zp);
    Zp = fmaf(kR3, s_zend[tid + 5], Zp);
    Zp = fmaf(kR4, s_zend[tid + 4], Zp);
    Zp = fmaf(kR5, s_zend[tid + 3], Zp);
    Zp = fmaf(kR6, s_zend[tid + 2], Zp);
    Zp = fmaf(kR7, s_zend[tid + 1], Zp);
    Zp = fmaf(kR8, s_zend[tid + 0], Zp);
    s_zp[tid] = Zp;
  }
  __syncthreads();

  // ---- Coalesced store + correction: z_exact(s) = z_loc(s)+0.97^(s+1)*Zp.
  // Output k lives in slot k+11 (written by lane k+9). Lane-consecutive
  // float4s: full 1 KB bursts per wave (R8/R9 lesson).
  {
    const int nv4 = min(kEmitH, kH - hbase) * 10;
    vfloat4* __restrict__ ob =
        (vfloat4*)(out + (size_t)b * kL + (size_t)hbase * kHS);
#pragma unroll 1
    for (int i = tid; i < nv4; i += kThreads) {
      const int k = i / 10;  // half-frame within block
      const int j = i - 10 * k;
      const vfloat4 h = *(const vfloat4*)(s_x + (k + 11) * kSlotW + 4 * j);
      const float Zp = s_zp[k];
      const float ee = __builtin_exp2f(kLg97 * (float)(4 * j + 1));
      vfloat4 v;
      v.x = fmaf(ee, Zp, h.x);
      v.y = fmaf(ee * 0.97f, Zp, h.y);
      v.z = fmaf(ee * 0.9409f, Zp, h.z);
      v.w = fmaf(ee * 0.912673f, Zp, h.w);
      ob[i] = v;
    }
  }
}
#undef AR_SAMPLE

extern "C" void kernel_launch(void* const* d_in, const int* in_sizes, int n_in,
                              void* d_out, int out_size, void* d_ws,
                              size_t ws_size, hipStream_t stream) {
  const float* excit = (const float*)d_in[0];  // (B, L, 1) fp32
  const float* coef = (const float*)d_in[1];   // (B, F, 16) fp32
  float* out = (float*)d_out;                  // (B, L, 1) fp32

  dim3 grid(kCols, kB);  // 51 x 64 blocks of 128
  lpc_synth_kernel<<<grid, kThreads, 0, stream>>>(excit, coef, out);
}